// Round 10
// baseline (278.967 us; speedup 1.0000x reference)
//
#include <hip/hip_runtime.h>

// ---------- constants for this problem ----------
// B=4, N=2048, C=1024, H=16, D=64; M = B*N = 8192
#define MM   8192
#define CC   1024
#define F3   3072
#define NN   2048
#define HH   16
#define DD   64
// q scale: D^-0.5 * log2(e), folded into q during RoPE so softmax uses exp2
#define QSCALE 0.1803368801111731f

typedef __attribute__((ext_vector_type(8))) __bf16 bf16x8;
typedef __attribute__((ext_vector_type(4))) float floatx4;
typedef __attribute__((ext_vector_type(4))) unsigned uintx4;

__device__ __forceinline__ unsigned short f2b(float f) {
  union { float f; unsigned int u; } v; v.f = f;
  unsigned int r = v.u + 0x7fffu + ((v.u >> 16) & 1u);
  return (unsigned short)(r >> 16);
}
__device__ __forceinline__ float b2f(unsigned short b) {
  union { unsigned int u; float f; } v; v.u = ((unsigned int)b) << 16;
  return v.f;
}

// async global->LDS, 16B per lane. LDS dest is wave-uniform base + lane*16,
// so the LDS layout must be lane-linear (no padding) in chunk order.
__device__ __forceinline__ void gl_lds16(const unsigned short* g, unsigned short* l) {
  __builtin_amdgcn_global_load_lds((const __attribute__((address_space(1))) void*)g,
                                   (__attribute__((address_space(3))) void*)l, 16, 0, 0);
}

// ---------- fp32 -> bf16 conversion (vectorized x4) ----------
__global__ __launch_bounds__(256) void f32_to_bf16_k(const float* __restrict__ in,
                                                     unsigned short* __restrict__ out, int n4) {
  int i = blockIdx.x * 256 + threadIdx.x;
  if (i < n4) {
    float4 v = ((const float4*)in)[i];
    ushort4 o;
    o.x = f2b(v.x); o.y = f2b(v.y); o.z = f2b(v.z); o.w = f2b(v.w);
    ((ushort4*)out)[i] = o;
  }
}

// ---------- GEMM1: 256x256 dbuf 4-PHASE (R10) ----------
// R9 diagnosis: gemm_p's 64x64/wave tile is LDS-BW-bound by construction
// (32 FLOP/LDS-byte < required ~53). 256^2 with 128x64/wave (43.7) is the
// only escape. R6's 256^2 failed on SCHEDULE (coarse all-reads->all-MFMA;
// m196 anti-pattern), not geometry. This is the m201-style phase-split:
//  * per K-tile, 4 phases: {reads for one 16-MFMA quadrant; barrier;
//    setprio+16 MFMA; barrier}. Reads distributed, never >12 bunched.
//  * register TIME-SHARE: afA (im0-3) lives ph0-1, overwritten by afB
//    (im4-7) in ph2 -> live regs ~222, no spill at 2 waves/SIMD.
//  * STAGE(t+1 -> OTHER buffer) issued whole at ph0: no WAR (different
//    buffer, whose t-1 contents were consumed last iter), ~3 phases
//    (>900cy) of flight before the vmcnt(0) at iter end => near-free.
//    (R7 lesson: prefetch window must exceed HBM latency — here it does.)
//    Correctness does NOT depend on phase pacing: only vmcnt(0)+barrier
//    before buffer switch.
//  * staging swizzle + read XOR verbatim from R6 (verified: 0 conflicts,
//    refcheck passed). RoPE/epilogue row algebra verbatim from R6 (passed).
//  * grid 384 (32x12): 1.5 rounds at 1 blk/CU — imbalance accepted.
template <int F, bool BF16OUT, bool ROPE>
__global__ __launch_bounds__(512, 2) void gemm256v2(const unsigned short* __restrict__ A,
                                                    const unsigned short* __restrict__ Bm,
                                                    void* __restrict__ Cout,
                                                    const float* __restrict__ bias,
                                                    const float* __restrict__ rcp,
                                                    const float* __restrict__ spp, int K) {
  __shared__ alignas(16) unsigned short lA[2][256 * 64];
  __shared__ alignas(16) unsigned short lB[2][256 * 64];
  const int tid = threadIdx.x, lane = tid & 63, wave = tid >> 6;
  const int r16 = lane & 15, q4 = lane >> 4;
  const int wm = wave & 1, wn = wave >> 1;

  // XCD-aware bijective remap (384 = 8 XCD x 48 slots)
  const int id = blockIdx.x;
  const int xcd = id & 7, slot = id >> 3;
  const int rx = xcd * 4 + (slot & 3), cy = slot >> 2;
  const int rowBase = rx * 256, colBase = cy * 256;

  // stage chunks: 2048 of 16B for A and for B -> 4+4 per thread (R6 verbatim)
#define CHOFF(base, c) ((size_t)((base) + ((c) >> 3)) * K + ((((c) & 7) ^ (((c) >> 3) & 7)) << 3))
  size_t aoff[4], boff[4];
#pragma unroll
  for (int i = 0; i < 4; ++i) {
    aoff[i] = CHOFF(rowBase, tid + i * 512);
    boff[i] = CHOFF(colBase, tid + i * 512);
  }
#undef CHOFF

#define STAGEP(kt, bsel) do { const int _k0 = (kt) * 64; \
    gl_lds16(A + aoff[0] + _k0, &lA[bsel][(tid) * 8]); \
    gl_lds16(A + aoff[1] + _k0, &lA[bsel][(tid + 512) * 8]); \
    gl_lds16(A + aoff[2] + _k0, &lA[bsel][(tid + 1024) * 8]); \
    gl_lds16(A + aoff[3] + _k0, &lA[bsel][(tid + 1536) * 8]); \
    gl_lds16(Bm + boff[0] + _k0, &lB[bsel][(tid) * 8]); \
    gl_lds16(Bm + boff[1] + _k0, &lB[bsel][(tid + 512) * 8]); \
    gl_lds16(Bm + boff[2] + _k0, &lB[bsel][(tid + 1024) * 8]); \
    gl_lds16(Bm + boff[3] + _k0, &lB[bsel][(tid + 1536) * 8]); } while (0)

  floatx4 acc[8][4];
  const floatx4 z = {0.f, 0.f, 0.f, 0.f};
#pragma unroll
  for (int i = 0; i < 8; ++i)
#pragma unroll
    for (int j = 0; j < 4; ++j) acc[i][j] = z;

  const int nt = K / 64;   // 16

  // prologue: land tile 0
  STAGEP(0, 0);
  asm volatile("s_waitcnt vmcnt(0)" ::: "memory");
  __builtin_amdgcn_s_barrier();
  __builtin_amdgcn_sched_barrier(0);

  for (int t = 0; t < nt; ++t) {
    const int p = t & 1;
    const unsigned short* la = &lA[p][0];
    const unsigned short* lb = &lB[p][0];

    // ---- phase 0: STAGE(t+1 -> other buf) + reads for quadrant 0 ----
    if (t + 1 < nt) STAGEP(t + 1, p ^ 1);
    bf16x8 af[4][2], bv[4][2];
#pragma unroll
    for (int im = 0; im < 4; ++im) {
      int row = wm * 128 + im * 16 + r16, r7 = row & 7;
      af[im][0] = *(const bf16x8*)(la + row * 64 + ((q4 ^ r7) << 3));
      af[im][1] = *(const bf16x8*)(la + row * 64 + (((4 + q4) ^ r7) << 3));
    }
#pragma unroll
    for (int jf = 0; jf < 2; ++jf) {
      int row = wn * 64 + jf * 16 + r16, r7 = row & 7;
      bv[jf][0] = *(const bf16x8*)(lb + row * 64 + ((q4 ^ r7) << 3));
      bv[jf][1] = *(const bf16x8*)(lb + row * 64 + (((4 + q4) ^ r7) << 3));
    }
    __builtin_amdgcn_s_barrier();
    __builtin_amdgcn_s_setprio(1);
#pragma unroll
    for (int jf = 0; jf < 2; ++jf)
#pragma unroll
      for (int im = 0; im < 4; ++im) {
        acc[im][jf] = __builtin_amdgcn_mfma_f32_16x16x32_bf16(af[im][0], bv[jf][0], acc[im][jf], 0, 0, 0);
        acc[im][jf] = __builtin_amdgcn_mfma_f32_16x16x32_bf16(af[im][1], bv[jf][1], acc[im][jf], 0, 0, 0);
      }
    __builtin_amdgcn_s_setprio(0);
    __builtin_amdgcn_s_barrier();

    // ---- phase 1: reads bv[2..3], MFMA im0-3 x jf2-3 ----
#pragma unroll
    for (int jf = 2; jf < 4; ++jf) {
      int row = wn * 64 + jf * 16 + r16, r7 = row & 7;
      bv[jf][0] = *(const bf16x8*)(lb + row * 64 + ((q4 ^ r7) << 3));
      bv[jf][1] = *(const bf16x8*)(lb + row * 64 + (((4 + q4) ^ r7) << 3));
    }
    __builtin_amdgcn_s_barrier();
    __builtin_amdgcn_s_setprio(1);
#pragma unroll
    for (int jf = 2; jf < 4; ++jf)
#pragma unroll
      for (int im = 0; im < 4; ++im) {
        acc[im][jf] = __builtin_amdgcn_mfma_f32_16x16x32_bf16(af[im][0], bv[jf][0], acc[im][jf], 0, 0, 0);
        acc[im][jf] = __builtin_amdgcn_mfma_f32_16x16x32_bf16(af[im][1], bv[jf][1], acc[im][jf], 0, 0, 0);
      }
    __builtin_amdgcn_s_setprio(0);
    __builtin_amdgcn_s_barrier();

    // ---- phase 2: overwrite af with im4-7 rows, MFMA im4-7 x jf0-1 ----
#pragma unroll
    for (int im = 0; im < 4; ++im) {
      int row = wm * 128 + (im + 4) * 16 + r16, r7 = row & 7;
      af[im][0] = *(const bf16x8*)(la + row * 64 + ((q4 ^ r7) << 3));
      af[im][1] = *(const bf16x8*)(la + row * 64 + (((4 + q4) ^ r7) << 3));
    }
    __builtin_amdgcn_s_barrier();
    __builtin_amdgcn_s_setprio(1);
#pragma unroll
    for (int jf = 0; jf < 2; ++jf)
#pragma unroll
      for (int im = 0; im < 4; ++im) {
        acc[im + 4][jf] = __builtin_amdgcn_mfma_f32_16x16x32_bf16(af[im][0], bv[jf][0], acc[im + 4][jf], 0, 0, 0);
        acc[im + 4][jf] = __builtin_amdgcn_mfma_f32_16x16x32_bf16(af[im][1], bv[jf][1], acc[im + 4][jf], 0, 0, 0);
      }
    __builtin_amdgcn_s_setprio(0);
    __builtin_amdgcn_s_barrier();

    // ---- phase 3: MFMA im4-7 x jf2-3, then drain stage + switch ----
    __builtin_amdgcn_s_setprio(1);
#pragma unroll
    for (int jf = 2; jf < 4; ++jf)
#pragma unroll
      for (int im = 0; im < 4; ++im) {
        acc[im + 4][jf] = __builtin_amdgcn_mfma_f32_16x16x32_bf16(af[im][0], bv[jf][0], acc[im + 4][jf], 0, 0, 0);
        acc[im + 4][jf] = __builtin_amdgcn_mfma_f32_16x16x32_bf16(af[im][1], bv[jf][1], acc[im + 4][jf], 0, 0, 0);
      }
    __builtin_amdgcn_s_setprio(0);
    // t+1's loads were issued a full iteration (~3 phases) ago -> near-free
    asm volatile("s_waitcnt vmcnt(0)" ::: "memory");
    __builtin_amdgcn_s_barrier();
    __builtin_amdgcn_sched_barrier(0);
  }
#undef STAGEP

  if (ROPE) {
    int head = (colBase >> 6) + wn;          // q:0-15, k:16-31, v:32-47
    if (head < 32) {
      const bool isq = head < 16;
#pragma unroll
      for (int im = 0; im < 8; ++im)
#pragma unroll
        for (int jf = 0; jf < 2; ++jf)
#pragma unroll
          for (int r = 0; r < 4; ++r) {
            int grow = rowBase + wm * 128 + im * 16 + q4 * 4 + r;
            int n = grow & (NN - 1);
            int dp = jf * 16 + r16;          // 0..31
            float x0 = acc[im][jf][r], x1 = acc[im][jf + 2][r];
            float c0 = rcp[n * DD + dp],      s0v = spp[n * DD + dp];
            float c1 = rcp[n * DD + dp + 32], s1v = spp[n * DD + dp + 32];
            float y0 = x0 * c0 - x1 * s0v;
            float y1 = x1 * c1 + x0 * s1v;
            if (isq) { y0 *= QSCALE; y1 *= QSCALE; }
            acc[im][jf][r] = y0;
            acc[im][jf + 2][r] = y1;
          }
    }
  }

#pragma unroll
  for (int im = 0; im < 8; ++im)
#pragma unroll
    for (int jf = 0; jf < 4; ++jf)
#pragma unroll
      for (int r = 0; r < 4; ++r) {
        int grow = rowBase + wm * 128 + im * 16 + q4 * 4 + r;
        int gcol = colBase + wn * 64 + jf * 16 + r16;
        if (BF16OUT)
          ((unsigned short*)Cout)[(size_t)grow * F + gcol] = f2b(acc[im][jf][r]);
        else
          ((float*)Cout)[(size_t)grow * F + gcol] = acc[im][jf][r] + bias[gcol];
      }
}

// ---------- GEMM2: 128x256 triple-buffered pipelined (R5, VERIFIED) ----------
// Kept for GEMM2: 256-block grid exactly fills the chip (256^2 would be
// 128 blocks = half idle). Note: 144 KiB LDS -> 1 block/CU; 64x64/wave is
// LDS-BW-capped (~612 TF) but GEMM2 is only 17.2 GFLOP.
template <int F, bool BF16OUT, bool ROPE>
__global__ __launch_bounds__(512, 2) void gemm_p(const unsigned short* __restrict__ A,
                                                 const unsigned short* __restrict__ Bm,
                                                 void* __restrict__ Cout,
                                                 const float* __restrict__ bias,
                                                 const float* __restrict__ rcp,
                                                 const float* __restrict__ spp, int K) {
  __shared__ alignas(16) unsigned short lA[3][128 * 64];
  __shared__ alignas(16) unsigned short lB[3][256 * 64];
  const int tid = threadIdx.x, lane = tid & 63, wave = tid >> 6;
  const int r16 = lane & 15, q4 = lane >> 4;
  const int wm = wave & 1, wn = wave >> 1;

  const int id = blockIdx.x;
  const int xcd = id & 7, slot = id >> 3;
  const int rx = xcd * 8 + (slot & 7), cy = slot >> 3;
  const int rowBase = rx * 128, colBase = cy * 256;

  const int cA0 = tid, cA1 = tid + 512;
  const int cB0 = tid, cB1 = tid + 512, cB2 = tid + 1024, cB3 = tid + 1536;
#define CHOFF(base, c) ((size_t)((base) + ((c) >> 3)) * K + ((((c) & 7) ^ (((c) >> 3) & 7)) << 3))
  const size_t aoff0 = CHOFF(rowBase, cA0), aoff1 = CHOFF(rowBase, cA1);
  const size_t boff0 = CHOFF(colBase, cB0), boff1 = CHOFF(colBase, cB1);
  const size_t boff2 = CHOFF(colBase, cB2), boff3 = CHOFF(colBase, cB3);
#undef CHOFF

#define STAGEP(kt, bsel) do { const int _k0 = (kt) * 64; \
    gl_lds16(A + aoff0 + _k0, &lA[bsel][cA0 * 8]); \
    gl_lds16(A + aoff1 + _k0, &lA[bsel][cA1 * 8]); \
    gl_lds16(Bm + boff0 + _k0, &lB[bsel][cB0 * 8]); \
    gl_lds16(Bm + boff1 + _k0, &lB[bsel][cB1 * 8]); \
    gl_lds16(Bm + boff2 + _k0, &lB[bsel][cB2 * 8]); \
    gl_lds16(Bm + boff3 + _k0, &lB[bsel][cB3 * 8]); } while (0)

  floatx4 acc[4][4];
  const floatx4 z = {0.f, 0.f, 0.f, 0.f};
#pragma unroll
  for (int i = 0; i < 4; ++i)
#pragma unroll
    for (int j = 0; j < 4; ++j) acc[i][j] = z;

  const int nt = K / 64;   // 16

  STAGEP(0, 0);
  STAGEP(1, 1);
  STAGEP(2, 2);
  asm volatile("s_waitcnt vmcnt(12)" ::: "memory");
  __builtin_amdgcn_s_barrier();
  __builtin_amdgcn_sched_barrier(0);

  int bs = 0;
  for (int t = 0; t < nt; ++t) {
    const unsigned short* la = &lA[bs][0];
    const unsigned short* lb = &lB[bs][0];
    bf16x8 af[4][2], bv[4][2];
#pragma unroll
    for (int im = 0; im < 4; ++im) {
      int row = wm * 64 + im * 16 + r16, r7 = row & 7;
      af[im][0] = *(const bf16x8*)(la + row * 64 + ((q4 ^ r7) << 3));
      af[im][1] = *(const bf16x8*)(la + row * 64 + (((4 + q4) ^ r7) << 3));
    }
#pragma unroll
    for (int jf = 0; jf < 4; ++jf) {
      int row = wn * 64 + jf * 16 + r16, r7 = row & 7;
      bv[jf][0] = *(const bf16x8*)(lb + row * 64 + ((q4 ^ r7) << 3));
      bv[jf][1] = *(const bf16x8*)(lb + row * 64 + (((4 + q4) ^ r7) << 3));
    }
    __builtin_amdgcn_s_setprio(1);
#pragma unroll
    for (int jf = 0; jf < 4; ++jf)
#pragma unroll
      for (int im = 0; im < 4; ++im) {
        acc[im][jf] = __builtin_amdgcn_mfma_f32_16x16x32_bf16(af[im][0], bv[jf][0], acc[im][jf], 0, 0, 0);
        acc[im][jf] = __builtin_amdgcn_mfma_f32_16x16x32_bf16(af[im][1], bv[jf][1], acc[im][jf], 0, 0, 0);
      }
    __builtin_amdgcn_s_setprio(0);

    __builtin_amdgcn_s_barrier();
    __builtin_amdgcn_sched_barrier(0);
    if (t + 3 < nt) {
      STAGEP(t + 3, bs);
      asm volatile("s_waitcnt vmcnt(12)" ::: "memory");
    } else {
      asm volatile("s_waitcnt vmcnt(0)" ::: "memory");
    }
    __builtin_amdgcn_sched_barrier(0);
    __builtin_amdgcn_s_barrier();
    __builtin_amdgcn_sched_barrier(0);
    bs = (bs == 2) ? 0 : bs + 1;
  }
#undef STAGEP

  if (ROPE) {
    int head = (colBase >> 6) + wn;
    if (head < 32) {
      const bool isq = head < 16;
#pragma unroll
      for (int im = 0; im < 4; ++im)
#pragma unroll
        for (int jf = 0; jf < 2; ++jf)
#pragma unroll
          for (int r = 0; r < 4; ++r) {
            int grow = rowBase + wm * 64 + im * 16 + q4 * 4 + r;
            int n = grow & (NN - 1);
            int dp = jf * 16 + r16;
            float x0 = acc[im][jf][r], x1 = acc[im][jf + 2][r];
            float c0 = rcp[n * DD + dp],      s0v = spp[n * DD + dp];
            float c1 = rcp[n * DD + dp + 32], s1v = spp[n * DD + dp + 32];
            float y0 = x0 * c0 - x1 * s0v;
            float y1 = x1 * c1 + x0 * s1v;
            if (isq) { y0 *= QSCALE; y1 *= QSCALE; }
            acc[im][jf][r] = y0;
            acc[im][jf + 2][r] = y1;
          }
    }
  }

#pragma unroll
  for (int im = 0; im < 4; ++im)
#pragma unroll
    for (int jf = 0; jf < 4; ++jf)
#pragma unroll
      for (int r = 0; r < 4; ++r) {
        int grow = rowBase + wm * 64 + im * 16 + q4 * 4 + r;
        int gcol = colBase + wn * 64 + jf * 16 + r16;
        if (BF16OUT)
          ((unsigned short*)Cout)[(size_t)grow * F + gcol] = f2b(acc[im][jf][r]);
        else
          ((float*)Cout)[(size_t)grow * F + gcol] = acc[im][jf][r] + bias[gcol];
      }
}

// ---------- flash attention v10 (R9, verified — UNCHANGED) ----------
// 512 blocks x 256 threads; q-tile 256, 4 FAT waves x 64 q-rows (read:MFMA
// ratio 4). Sigma-trick V placement; swapped QK^T; cvt_pk RNE; XCD swizzle;
// setprio. v_permlane16_swap_b32 BANNED (R1). Do NOT shrink q-tile (R3).
__global__ __launch_bounds__(256, 2) void attn_k(const unsigned short* __restrict__ qkv,
                                                 unsigned short* __restrict__ obuf) {
  __shared__ alignas(16) unsigned short sK[64 * 64];
  __shared__ alignas(16) unsigned short sVT[64 * 64];

  const int tid = threadIdx.x, lane = tid & 63, wave = tid >> 6;
  const int r16 = lane & 15, q4 = lane >> 4;

  const int id = blockIdx.x;                 // 0..511
  const int xcd = id & 7, slot = id >> 3;    // 64 slots/XCD
  const int bh = xcd * 8 + (slot >> 3);      // 8 bh per XCD
  const int q0 = (slot & 7) * 256;           // 8 q-tiles of 256 rows
  const int b = bh >> 4, h = bh & 15;
  const unsigned short* qbase = qkv + (size_t)(b * NN) * F3 + h * DD;

  bf16x8 qf[4][2];
#pragma unroll
  for (int im = 0; im < 4; ++im)
#pragma unroll
    for (int kk = 0; kk < 2; ++kk)
      qf[im][kk] = *(const bf16x8*)(qbase +
          (size_t)(q0 + wave * 64 + im * 16 + r16) * F3 + kk * 32 + q4 * 8);

  const floatx4 z = {0.f, 0.f, 0.f, 0.f};
  floatx4 o[4][4];
  float lacc[4] = {0.f, 0.f, 0.f, 0.f};
#pragma unroll
  for (int im = 0; im < 4; ++im)
    for (int jd = 0; jd < 4; ++jd) o[im][jd] = z;

  const int krow0 = tid >> 3, kc8 = tid & 7;
  const int vkvp = tid >> 3, vc8 = tid & 7;
  const int mp = (vkvp & 16) | ((vkvp & 4) << 1) | ((vkvp & 2) << 1) |
                 ((vkvp & 8) >> 2) | (vkvp & 1);

  const unsigned short* kvb = qbase;
  int4 kreg0 = *(const int4*)(kvb + (size_t)krow0 * F3 + CC + kc8 * 8);
  int4 kreg1 = *(const int4*)(kvb + (size_t)(krow0 + 32) * F3 + CC + kc8 * 8);
  int4 vreg0 = *(const int4*)(kvb + (size_t)(2 * vkvp) * F3 + 2 * CC + vc8 * 8);
  int4 vreg1 = *(const int4*)(kvb + (size_t)(2 * vkvp + 1) * F3 + 2 * CC + vc8 * 8);

  for (int t = 0; t < NN / 64; ++t) {
    __syncthreads();   // previous iter's LDS reads complete

    *(int4*)(&sK[krow0 * 64 + ((kc8 ^ (krow0 & 7)) << 3)]) = kreg0;
    *(int4*)(&sK[(krow0 + 32) * 64 + ((kc8 ^ ((krow0 + 32) & 7)) << 3)]) = kreg1;
    {
      const unsigned* a0 = (const unsigned*)&vreg0;
      const unsigned* a1 = (const unsigned*)&vreg1;
#pragma unroll
      for (int w = 0; w < 4; ++w) {
        unsigned lo = __builtin_amdgcn_perm(a1[w], a0[w], 0x05040100u);
        unsigned hi = __builtin_amdgcn_perm(a1[w], a0[w], 0x07060302u);
        int d0 = vc8 * 8 + 2 * w;
        int sw0 = (2 * w + vc8) & 7;
        int sw1 = (2 * w + 1 + vc8) & 7;
        *(unsigned*)(&sVT[d0 * 64 + (((mp >> 2) ^ sw0) << 3) + 2 * (mp & 3)]) = lo;
        *(unsigned*)(&sVT[(d0 + 1) * 64 + (((mp >> 2) ^ sw1) << 3) + 2 * (mp & 3)]) = hi;
      }
    }

    if (t + 1 < NN / 64) {
      const unsigned short* nb = qkv + (size_t)(b * NN + (t + 1) * 64) * F3 + h * DD;
      kreg0 = *(const int4*)(nb + (size_t)krow0 * F3 + CC + kc8 * 8);
      kreg1 = *(const int4*)(nb + (size_t)(krow0 + 32) * F3 + CC + kc8 * 8);
      vreg0 = *(const int4*)(nb + (size_t)(2 * vkvp) * F3 + 2 * CC + vc8 * 8);
      vreg1 = *(const int4*)(nb + (size_t)(2 * vkvp + 1) * F3 + 2 * CC + vc8 * 8);
    }

    __syncthreads();   // K_t/V_t visible

    floatx4 s[4][4];
    __builtin_amdgcn_s_setprio(1);
#pragma unroll
    for (int jn = 0; jn < 4; ++jn) {
      int row = jn * 16 + r16;
      bf16x8 kf0 = *(const bf16x8*)(&sK[row * 64 + ((q4 ^ (row & 7)) << 3)]);
      bf16x8 kf1 = *(const bf16x8*)(&sK[row * 64 + (((4 + q4) ^ (row & 7)) << 3)]);
#pragma unroll
      for (int im = 0; im < 4; ++im) {
        floatx4 a = z;
        a = __builtin_amdgcn_mfma_f32_16x16x32_bf16(kf0, qf[im][0], a, 0, 0, 0);
        a = __builtin_amdgcn_mfma_f32_16x16x32_bf16(kf1, qf[im][1], a, 0, 0, 0);
        s[im][jn] = a;
      }
    }
    __builtin_amdgcn_s_setprio(0);

    bf16x8 pf[4][2];
#pragma unroll
    for (int im = 0; im < 4; ++im) {
#pragma unroll
      for (int kk = 0; kk < 2; ++kk) {
        uintx4 pk;
#pragma unroll
        for (int j2 = 0; j2 < 2; ++j2) {
          int jn = 2 * kk + j2;
          float p0 = __builtin_amdgcn_exp2f(s[im][jn][0]);
          float p1 = __builtin_amdgcn_exp2f(s[im][jn][1]);
          float p2 = __builtin_amdgcn_exp2f(s[im][jn][2]);
          float p3 = __builtin_amdgcn_exp2f(s[im][jn][3]);
          lacc[im] += (p0 + p1) + (p2 + p3);
          asm("v_cvt_pk_bf16_f32 %0, %1, %2" : "=v"(pk[2 * j2]) : "v"(p0), "v"(p1));
          asm("v_cvt_pk_bf16_f32 %0, %1, %2" : "=v"(pk[2 * j2 + 1]) : "v"(p2), "v"(p3));
        }
        pf[im][kk] = __builtin_bit_cast(bf16x8, pk);
      }
    }

    __builtin_amdgcn_s_setprio(1);
#pragma unroll
    for (int jd = 0; jd < 4; ++jd) {
      int d = jd * 16 + r16;
      int swr = (d + (d >> 3)) & 7;
      bf16x8 vf0 = *(const bf16x8*)(&sVT[d * 64 + ((q4 ^ swr) << 3)]);
      bf16x8 vf1 = *(const bf16x8*)(&sVT[d * 64 + (((4 + q4) ^ swr) << 3)]);
#pragma unroll
      for (int im = 0; im < 4; ++im) {
        o[im][jd] = __builtin_amdgcn_mfma_f32_16x16x32_bf16(pf[im][0], vf0, o[im][jd], 0, 0, 0);
        o[im][jd] = __builtin_amdgcn_mfma_f32_16x16x32_bf16(pf[im][1], vf1, o[im][jd], 0, 0, 0);
      }
    }
    __builtin_amdgcn_s_setprio(0);
  }

#pragma unroll
  for (int im = 0; im < 4; ++im) {
    float l = lacc[im];
    l += __shfl_xor(l, 16);
    l += __shfl_xor(l, 32);
    float inv = 1.0f / l;
#pragma unroll
    for (int r = 0; r < 4; ++r) {
      float invr = __shfl(inv, q4 * 4 + r);
      int row = q0 + wave * 64 + im * 16 + q4 * 4 + r;
#pragma unroll
      for (int jd = 0; jd < 4; ++jd) {
        int col = h * DD + jd * 16 + r16;
        obuf[(size_t)(b * NN + row) * CC + col] = f2b(o[im][jd][r] * invr);
      }
    }
  }
}

// ---------- launcher ----------
extern "C" void kernel_launch(void* const* d_in, const int* in_sizes, int n_in,
                              void* d_out, int out_size, void* d_ws, size_t ws_size,
                              hipStream_t stream) {
  const float* x     = (const float*)d_in[0];
  const float* rc    = (const float*)d_in[1];
  const float* rs    = (const float*)d_in[2];
  const float* wqkv  = (const float*)d_in[3];
  const float* wproj = (const float*)d_in[4];
  const float* bproj = (const float*)d_in[5];
  float* out = (float*)d_out;

  char* w = (char*)d_ws;
  unsigned short* xb     = (unsigned short*)(w);                       // 16,777,216 B
  unsigned short* wqkvb  = (unsigned short*)(w + 16777216);            //  6,291,456 B
  unsigned short* wprojb = (unsigned short*)(w + 23068672);            //  2,097,152 B
  unsigned short* qkvb   = (unsigned short*)(w + 25165824);            // 50,331,648 B
  unsigned short* obuf   = (unsigned short*)(w + 75497472);            // 16,777,216 B

  f32_to_bf16_k<<<(MM * CC / 4 + 255) / 256, 256, 0, stream>>>(x, xb, MM * CC / 4);
  f32_to_bf16_k<<<(F3 * CC / 4 + 255) / 256, 256, 0, stream>>>(wqkv, wqkvb, F3 * CC / 4);
  f32_to_bf16_k<<<(CC * CC / 4 + 255) / 256, 256, 0, stream>>>(wproj, wprojb, CC * CC / 4);

  // GEMM1 with fused RoPE epilogue: 256x256 4-phase, grid 32x12 = 384
  gemm256v2<F3, true, true><<<384, 512, 0, stream>>>(
      xb, wqkvb, qkvb, nullptr, rc, rs, CC);

  // attn: 512 blocks x 256 threads (q-tile 256, 4 waves x 64 rows)
  attn_k<<<512, 256, 0, stream>>>(qkvb, obuf);

  // GEMM2: 128x256 tiles, grid 256 = exactly 1 full round
  gemm_p<CC, false, false><<<256, 512, 0, stream>>>(
      obuf, wprojb, out, bproj, nullptr, nullptr, CC);
}

// Round 11
// 263.481 us; speedup vs baseline: 1.0588x; 1.0588x over previous
//
#include <hip/hip_runtime.h>

// ---------- constants for this problem ----------
// B=4, N=2048, C=1024, H=16, D=64; M = B*N = 8192
#define MM   8192
#define CC   1024
#define F3   3072
#define NN   2048
#define HH   16
#define DD   64
// q scale: D^-0.5 * log2(e), folded into q during RoPE so softmax uses exp2
#define QSCALE 0.1803368801111731f

typedef __attribute__((ext_vector_type(8))) __bf16 bf16x8;
typedef __attribute__((ext_vector_type(4))) float floatx4;
typedef __attribute__((ext_vector_type(4))) unsigned uintx4;

__device__ __forceinline__ unsigned short f2b(float f) {
  union { float f; unsigned int u; } v; v.f = f;
  unsigned int r = v.u + 0x7fffu + ((v.u >> 16) & 1u);
  return (unsigned short)(r >> 16);
}
__device__ __forceinline__ float b2f(unsigned short b) {
  union { unsigned int u; float f; } v; v.u = ((unsigned int)b) << 16;
  return v.f;
}

// async global->LDS, 16B per lane. LDS dest is wave-uniform base + lane*16,
// so the LDS layout must be lane-linear (no padding) in chunk order.
__device__ __forceinline__ void gl_lds16(const unsigned short* g, unsigned short* l) {
  __builtin_amdgcn_global_load_lds((const __attribute__((address_space(1))) void*)g,
                                   (__attribute__((address_space(3))) void*)l, 16, 0, 0);
}

// ---------- merged fp32 -> bf16 conversion (R11: 3 dispatches -> 1) ----------
// Grid-strided over all three arrays; branch is coherent except at the two
// boundaries. 2048 blocks x 256 thr, 6 float4/thread.
__global__ __launch_bounds__(256) void cvt_all_k(const float* __restrict__ x,
                                                 const float* __restrict__ wqkv,
                                                 const float* __restrict__ wproj,
                                                 unsigned short* __restrict__ xb,
                                                 unsigned short* __restrict__ wqkvb,
                                                 unsigned short* __restrict__ wprojb) {
  const int N0 = MM * CC / 4, N1 = F3 * CC / 4, N2 = CC * CC / 4;
  const int total = N0 + N1 + N2;
  const int stride = (int)gridDim.x * 256;
  for (int i = blockIdx.x * 256 + threadIdx.x; i < total; i += stride) {
    const float* src;
    unsigned short* dst;
    int j;
    if (i < N0)            { src = x;     dst = xb;     j = i; }
    else if (i < N0 + N1)  { src = wqkv;  dst = wqkvb;  j = i - N0; }
    else                   { src = wproj; dst = wprojb; j = i - N0 - N1; }
    float4 v = ((const float4*)src)[j];
    ushort4 o;
    o.x = f2b(v.x); o.y = f2b(v.y); o.z = f2b(v.z); o.w = f2b(v.w);
    ((ushort4*)dst)[j] = o;
  }
}

// ---------- GEMM: 128x256 triple-buffered pipelined (R5, VERIFIED BEST) ----------
// GEMM history: R4 gemm_bt(128x128/BK32/syncthreads)=88.9us; R5 THIS=84.3us
// (best); R6 256x256 coarse=108; R7 256x128/BK32 depth-2=regression (iter
// too short vs ~900cy HBM latency); R10 256x256 4-phase=92.7. The 256^2
// path at K=1024 is DEAD in plain HIP here — do not revisit. Note (R10
// errata): ratio-2 read:MFMA is NOT LDS-BW-bound (m97 hit 912TF at ratio
// 2); the 84us band is prologue/drain + L2-feed at short K=1024.
template <int F, bool BF16OUT, bool ROPE>
__global__ __launch_bounds__(512, 2) void gemm_p(const unsigned short* __restrict__ A,
                                                 const unsigned short* __restrict__ Bm,
                                                 void* __restrict__ Cout,
                                                 const float* __restrict__ bias,
                                                 const float* __restrict__ rcp,
                                                 const float* __restrict__ spp, int K) {
  __shared__ alignas(16) unsigned short lA[3][128 * 64];
  __shared__ alignas(16) unsigned short lB[3][256 * 64];
  const int tid = threadIdx.x, lane = tid & 63, wave = tid >> 6;
  const int r16 = lane & 15, q4 = lane >> 4;
  const int wm = wave & 1, wn = wave >> 1;

  const int id = blockIdx.x;
  const int xcd = id & 7, slot = id >> 3;
  const int rx = xcd * 8 + (slot & 7), cy = slot >> 3;
  const int rowBase = rx * 128, colBase = cy * 256;

  const int cA0 = tid, cA1 = tid + 512;
  const int cB0 = tid, cB1 = tid + 512, cB2 = tid + 1024, cB3 = tid + 1536;
#define CHOFF(base, c) ((size_t)((base) + ((c) >> 3)) * K + ((((c) & 7) ^ (((c) >> 3) & 7)) << 3))
  const size_t aoff0 = CHOFF(rowBase, cA0), aoff1 = CHOFF(rowBase, cA1);
  const size_t boff0 = CHOFF(colBase, cB0), boff1 = CHOFF(colBase, cB1);
  const size_t boff2 = CHOFF(colBase, cB2), boff3 = CHOFF(colBase, cB3);
#undef CHOFF

#define STAGEP(kt, bsel) do { const int _k0 = (kt) * 64; \
    gl_lds16(A + aoff0 + _k0, &lA[bsel][cA0 * 8]); \
    gl_lds16(A + aoff1 + _k0, &lA[bsel][cA1 * 8]); \
    gl_lds16(Bm + boff0 + _k0, &lB[bsel][cB0 * 8]); \
    gl_lds16(Bm + boff1 + _k0, &lB[bsel][cB1 * 8]); \
    gl_lds16(Bm + boff2 + _k0, &lB[bsel][cB2 * 8]); \
    gl_lds16(Bm + boff3 + _k0, &lB[bsel][cB3 * 8]); } while (0)

  floatx4 acc[4][4];
  const floatx4 z = {0.f, 0.f, 0.f, 0.f};
#pragma unroll
  for (int i = 0; i < 4; ++i)
#pragma unroll
    for (int j = 0; j < 4; ++j) acc[i][j] = z;

  const int nt = K / 64;   // 16

  STAGEP(0, 0);
  STAGEP(1, 1);
  STAGEP(2, 2);
  asm volatile("s_waitcnt vmcnt(12)" ::: "memory");
  __builtin_amdgcn_s_barrier();
  __builtin_amdgcn_sched_barrier(0);

  int bs = 0;
  for (int t = 0; t < nt; ++t) {
    const unsigned short* la = &lA[bs][0];
    const unsigned short* lb = &lB[bs][0];
    bf16x8 af[4][2], bv[4][2];
#pragma unroll
    for (int im = 0; im < 4; ++im) {
      int row = wm * 64 + im * 16 + r16, r7 = row & 7;
      af[im][0] = *(const bf16x8*)(la + row * 64 + ((q4 ^ r7) << 3));
      af[im][1] = *(const bf16x8*)(la + row * 64 + (((4 + q4) ^ r7) << 3));
    }
#pragma unroll
    for (int jf = 0; jf < 4; ++jf) {
      int row = wn * 64 + jf * 16 + r16, r7 = row & 7;
      bv[jf][0] = *(const bf16x8*)(lb + row * 64 + ((q4 ^ r7) << 3));
      bv[jf][1] = *(const bf16x8*)(lb + row * 64 + (((4 + q4) ^ r7) << 3));
    }
    __builtin_amdgcn_s_setprio(1);
#pragma unroll
    for (int jf = 0; jf < 4; ++jf)
#pragma unroll
      for (int im = 0; im < 4; ++im) {
        acc[im][jf] = __builtin_amdgcn_mfma_f32_16x16x32_bf16(af[im][0], bv[jf][0], acc[im][jf], 0, 0, 0);
        acc[im][jf] = __builtin_amdgcn_mfma_f32_16x16x32_bf16(af[im][1], bv[jf][1], acc[im][jf], 0, 0, 0);
      }
    __builtin_amdgcn_s_setprio(0);

    __builtin_amdgcn_s_barrier();
    __builtin_amdgcn_sched_barrier(0);
    if (t + 3 < nt) {
      STAGEP(t + 3, bs);
      asm volatile("s_waitcnt vmcnt(12)" ::: "memory");
    } else {
      asm volatile("s_waitcnt vmcnt(0)" ::: "memory");
    }
    __builtin_amdgcn_sched_barrier(0);
    __builtin_amdgcn_s_barrier();
    __builtin_amdgcn_sched_barrier(0);
    bs = (bs == 2) ? 0 : bs + 1;
  }
#undef STAGEP

  if (ROPE) {
    int head = (colBase >> 6) + wn;
    if (head < 32) {
      const bool isq = head < 16;
#pragma unroll
      for (int im = 0; im < 4; ++im)
#pragma unroll
        for (int jf = 0; jf < 2; ++jf)
#pragma unroll
          for (int r = 0; r < 4; ++r) {
            int grow = rowBase + wm * 64 + im * 16 + q4 * 4 + r;
            int n = grow & (NN - 1);
            int dp = jf * 16 + r16;
            float x0 = acc[im][jf][r], x1 = acc[im][jf + 2][r];
            float c0 = rcp[n * DD + dp],      s0v = spp[n * DD + dp];
            float c1 = rcp[n * DD + dp + 32], s1v = spp[n * DD + dp + 32];
            float y0 = x0 * c0 - x1 * s0v;
            float y1 = x1 * c1 + x0 * s1v;
            if (isq) { y0 *= QSCALE; y1 *= QSCALE; }
            acc[im][jf][r] = y0;
            acc[im][jf + 2][r] = y1;
          }
    }
  }

#pragma unroll
  for (int im = 0; im < 4; ++im)
#pragma unroll
    for (int jf = 0; jf < 4; ++jf)
#pragma unroll
      for (int r = 0; r < 4; ++r) {
        int grow = rowBase + wm * 64 + im * 16 + q4 * 4 + r;
        int gcol = colBase + wn * 64 + jf * 16 + r16;
        if (BF16OUT)
          ((unsigned short*)Cout)[(size_t)grow * F + gcol] = f2b(acc[im][jf][r]);
        else
          ((float*)Cout)[(size_t)grow * F + gcol] = acc[im][jf][r] + bias[gcol];
      }
}

// ---------- flash attention v10 (R9, verified — UNCHANGED) ----------
// 512 blocks x 256 threads; q-tile 256, 4 FAT waves x 64 q-rows (read:MFMA
// ratio 4). Sigma-trick V placement; swapped QK^T; cvt_pk RNE; XCD swizzle;
// setprio. v_permlane16_swap_b32 BANNED (R1). Do NOT shrink q-tile (R3).
__global__ __launch_bounds__(256, 2) void attn_k(const unsigned short* __restrict__ qkv,
                                                 unsigned short* __restrict__ obuf) {
  __shared__ alignas(16) unsigned short sK[64 * 64];
  __shared__ alignas(16) unsigned short sVT[64 * 64];

  const int tid = threadIdx.x, lane = tid & 63, wave = tid >> 6;
  const int r16 = lane & 15, q4 = lane >> 4;

  const int id = blockIdx.x;                 // 0..511
  const int xcd = id & 7, slot = id >> 3;    // 64 slots/XCD
  const int bh = xcd * 8 + (slot >> 3);      // 8 bh per XCD
  const int q0 = (slot & 7) * 256;           // 8 q-tiles of 256 rows
  const int b = bh >> 4, h = bh & 15;
  const unsigned short* qbase = qkv + (size_t)(b * NN) * F3 + h * DD;

  bf16x8 qf[4][2];
#pragma unroll
  for (int im = 0; im < 4; ++im)
#pragma unroll
    for (int kk = 0; kk < 2; ++kk)
      qf[im][kk] = *(const bf16x8*)(qbase +
          (size_t)(q0 + wave * 64 + im * 16 + r16) * F3 + kk * 32 + q4 * 8);

  const floatx4 z = {0.f, 0.f, 0.f, 0.f};
  floatx4 o[4][4];
  float lacc[4] = {0.f, 0.f, 0.f, 0.f};
#pragma unroll
  for (int im = 0; im < 4; ++im)
    for (int jd = 0; jd < 4; ++jd) o[im][jd] = z;

  const int krow0 = tid >> 3, kc8 = tid & 7;
  const int vkvp = tid >> 3, vc8 = tid & 7;
  const int mp = (vkvp & 16) | ((vkvp & 4) << 1) | ((vkvp & 2) << 1) |
                 ((vkvp & 8) >> 2) | (vkvp & 1);

  const unsigned short* kvb = qbase;
  int4 kreg0 = *(const int4*)(kvb + (size_t)krow0 * F3 + CC + kc8 * 8);
  int4 kreg1 = *(const int4*)(kvb + (size_t)(krow0 + 32) * F3 + CC + kc8 * 8);
  int4 vreg0 = *(const int4*)(kvb + (size_t)(2 * vkvp) * F3 + 2 * CC + vc8 * 8);
  int4 vreg1 = *(const int4*)(kvb + (size_t)(2 * vkvp + 1) * F3 + 2 * CC + vc8 * 8);

  for (int t = 0; t < NN / 64; ++t) {
    __syncthreads();   // previous iter's LDS reads complete

    *(int4*)(&sK[krow0 * 64 + ((kc8 ^ (krow0 & 7)) << 3)]) = kreg0;
    *(int4*)(&sK[(krow0 + 32) * 64 + ((kc8 ^ ((krow0 + 32) & 7)) << 3)]) = kreg1;
    {
      const unsigned* a0 = (const unsigned*)&vreg0;
      const unsigned* a1 = (const unsigned*)&vreg1;
#pragma unroll
      for (int w = 0; w < 4; ++w) {
        unsigned lo = __builtin_amdgcn_perm(a1[w], a0[w], 0x05040100u);
        unsigned hi = __builtin_amdgcn_perm(a1[w], a0[w], 0x07060302u);
        int d0 = vc8 * 8 + 2 * w;
        int sw0 = (2 * w + vc8) & 7;
        int sw1 = (2 * w + 1 + vc8) & 7;
        *(unsigned*)(&sVT[d0 * 64 + (((mp >> 2) ^ sw0) << 3) + 2 * (mp & 3)]) = lo;
        *(unsigned*)(&sVT[(d0 + 1) * 64 + (((mp >> 2) ^ sw1) << 3) + 2 * (mp & 3)]) = hi;
      }
    }

    if (t + 1 < NN / 64) {
      const unsigned short* nb = qkv + (size_t)(b * NN + (t + 1) * 64) * F3 + h * DD;
      kreg0 = *(const int4*)(nb + (size_t)krow0 * F3 + CC + kc8 * 8);
      kreg1 = *(const int4*)(nb + (size_t)(krow0 + 32) * F3 + CC + kc8 * 8);
      vreg0 = *(const int4*)(nb + (size_t)(2 * vkvp) * F3 + 2 * CC + vc8 * 8);
      vreg1 = *(const int4*)(nb + (size_t)(2 * vkvp + 1) * F3 + 2 * CC + vc8 * 8);
    }

    __syncthreads();   // K_t/V_t visible

    floatx4 s[4][4];
    __builtin_amdgcn_s_setprio(1);
#pragma unroll
    for (int jn = 0; jn < 4; ++jn) {
      int row = jn * 16 + r16;
      bf16x8 kf0 = *(const bf16x8*)(&sK[row * 64 + ((q4 ^ (row & 7)) << 3)]);
      bf16x8 kf1 = *(const bf16x8*)(&sK[row * 64 + (((4 + q4) ^ (row & 7)) << 3)]);
#pragma unroll
      for (int im = 0; im < 4; ++im) {
        floatx4 a = z;
        a = __builtin_amdgcn_mfma_f32_16x16x32_bf16(kf0, qf[im][0], a, 0, 0, 0);
        a = __builtin_amdgcn_mfma_f32_16x16x32_bf16(kf1, qf[im][1], a, 0, 0, 0);
        s[im][jn] = a;
      }
    }
    __builtin_amdgcn_s_setprio(0);

    bf16x8 pf[4][2];
#pragma unroll
    for (int im = 0; im < 4; ++im) {
#pragma unroll
      for (int kk = 0; kk < 2; ++kk) {
        uintx4 pk;
#pragma unroll
        for (int j2 = 0; j2 < 2; ++j2) {
          int jn = 2 * kk + j2;
          float p0 = __builtin_amdgcn_exp2f(s[im][jn][0]);
          float p1 = __builtin_amdgcn_exp2f(s[im][jn][1]);
          float p2 = __builtin_amdgcn_exp2f(s[im][jn][2]);
          float p3 = __builtin_amdgcn_exp2f(s[im][jn][3]);
          lacc[im] += (p0 + p1) + (p2 + p3);
          asm("v_cvt_pk_bf16_f32 %0, %1, %2" : "=v"(pk[2 * j2]) : "v"(p0), "v"(p1));
          asm("v_cvt_pk_bf16_f32 %0, %1, %2" : "=v"(pk[2 * j2 + 1]) : "v"(p2), "v"(p3));
        }
        pf[im][kk] = __builtin_bit_cast(bf16x8, pk);
      }
    }

    __builtin_amdgcn_s_setprio(1);
#pragma unroll
    for (int jd = 0; jd < 4; ++jd) {
      int d = jd * 16 + r16;
      int swr = (d + (d >> 3)) & 7;
      bf16x8 vf0 = *(const bf16x8*)(&sVT[d * 64 + ((q4 ^ swr) << 3)]);
      bf16x8 vf1 = *(const bf16x8*)(&sVT[d * 64 + (((4 + q4) ^ swr) << 3)]);
#pragma unroll
      for (int im = 0; im < 4; ++im) {
        o[im][jd] = __builtin_amdgcn_mfma_f32_16x16x32_bf16(pf[im][0], vf0, o[im][jd], 0, 0, 0);
        o[im][jd] = __builtin_amdgcn_mfma_f32_16x16x32_bf16(pf[im][1], vf1, o[im][jd], 0, 0, 0);
      }
    }
    __builtin_amdgcn_s_setprio(0);
  }

#pragma unroll
  for (int im = 0; im < 4; ++im) {
    float l = lacc[im];
    l += __shfl_xor(l, 16);
    l += __shfl_xor(l, 32);
    float inv = 1.0f / l;
#pragma unroll
    for (int r = 0; r < 4; ++r) {
      float invr = __shfl(inv, q4 * 4 + r);
      int row = q0 + wave * 64 + im * 16 + q4 * 4 + r;
#pragma unroll
      for (int jd = 0; jd < 4; ++jd) {
        int col = h * DD + jd * 16 + r16;
        obuf[(size_t)(b * NN + row) * CC + col] = f2b(o[im][jd][r] * invr);
      }
    }
  }
}

// ---------- launcher ----------
extern "C" void kernel_launch(void* const* d_in, const int* in_sizes, int n_in,
                              void* d_out, int out_size, void* d_ws, size_t ws_size,
                              hipStream_t stream) {
  const float* x     = (const float*)d_in[0];
  const float* rc    = (const float*)d_in[1];
  const float* rs    = (const float*)d_in[2];
  const float* wqkv  = (const float*)d_in[3];
  const float* wproj = (const float*)d_in[4];
  const float* bproj = (const float*)d_in[5];
  float* out = (float*)d_out;

  char* w = (char*)d_ws;
  unsigned short* xb     = (unsigned short*)(w);                       // 16,777,216 B
  unsigned short* wqkvb  = (unsigned short*)(w + 16777216);            //  6,291,456 B
  unsigned short* wprojb = (unsigned short*)(w + 23068672);            //  2,097,152 B
  unsigned short* qkvb   = (unsigned short*)(w + 25165824);            // 50,331,648 B
  unsigned short* obuf   = (unsigned short*)(w + 75497472);            // 16,777,216 B

  // single merged conversion dispatch (R11: was 3 dispatches)
  cvt_all_k<<<2048, 256, 0, stream>>>(x, wqkv, wproj, xb, wqkvb, wprojb);

  // GEMM1 with fused RoPE epilogue: grid 64x12 tiles = 768 = 3 full rounds
  gemm_p<F3, true, true><<<768, 512, 0, stream>>>(
      xb, wqkvb, qkvb, nullptr, rc, rs, CC);

  // attn: 512 blocks x 256 threads (q-tile 256, 4 waves x 64 rows)
  attn_k<<<512, 256, 0, stream>>>(qkvb, obuf);

  // GEMM2: grid 64x4 = 256 = exactly 1 full round
  gemm_p<CC, false, false><<<256, 512, 0, stream>>>(
      obuf, wprojb, out, bproj, nullptr, nullptr, CC);
}